// Round 16
// baseline (213.435 us; speedup 1.0000x reference)
//
#include <hip/hip_runtime.h>
#include <hip/hip_bf16.h>
#include <stdint.h>

// WindowAttention: B_=4096 windows, N=64 tokens, C=192, H=6 heads, hd=32.
// Round 16: r15 (4-buffer rotation, barrier per 2 phases, 268us rocprof)
// with SPLIT-ACCUMULATOR gemm6: the 6-deep dependent MFMA chain (the largest
// serial term in all 48 phases, ~300cy) becomes two independent 3-chains
// (+1 vector add, ~160cy). Everything else byte-identical to r15.

#define NTOK 64
#define CDIM 192
#define KROW 40           // kh row stride (shorts): 80 B
#define VROW 72           // vth row stride (shorts): 144 B
#define CHUNK 3072        // shorts per 16x192 chunk
#define BUF 3072          // shorts per LDS buffer

typedef __attribute__((ext_vector_type(4))) float f32x4;
typedef __attribute__((ext_vector_type(8))) short bf16x8;

__device__ __forceinline__ short f2bf(float f) {
  __hip_bfloat16 h = __float2bfloat16(f);
  return *reinterpret_cast<short*>(&h);
}
__device__ __forceinline__ uint32_t pack2(float a, float b) {
  __hip_bfloat162 h2;
  h2.x = __float2bfloat16(a);
  h2.y = __float2bfloat16(b);                      // fuses to v_cvt_pk_bf16_f32
  return *reinterpret_cast<uint32_t*>(&h2);
}

// Cross-lane transpose (validated r2-r15).
__device__ __forceinline__ bf16x8 xpose(uint32_t A0, uint32_t A1,
                                        uint32_t B0, uint32_t B1,
                                        int s0, int hiSel) {
  uint32_t w[4];
  uint32_t a, b;
  a = (uint32_t)__shfl((int)A0, s0);      b = (uint32_t)__shfl((int)B0, s0);      w[0] = hiSel ? b : a;
  a = (uint32_t)__shfl((int)A1, s0);      b = (uint32_t)__shfl((int)B1, s0);      w[1] = hiSel ? b : a;
  a = (uint32_t)__shfl((int)A0, s0 + 16); b = (uint32_t)__shfl((int)B0, s0 + 16); w[2] = hiSel ? b : a;
  a = (uint32_t)__shfl((int)A1, s0 + 16); b = (uint32_t)__shfl((int)B1, s0 + 16); w[3] = hiSel ? b : a;
  return *reinterpret_cast<bf16x8*>(w);
}

#define MFMA16(A, B, C) __builtin_amdgcn_mfma_f32_16x16x32_bf16((A), (B), (C), 0, 0, 0)

// 6-step K=192 GEMM, TWO independent accumulator chains (3 deep each).
__device__ __forceinline__ f32x4 gemm6_w_af(const short* __restrict__ p0,
                                            const short* __restrict__ p1, int off,
                                            const bf16x8* __restrict__ af) {
  f32x4 a0 = {0.f, 0.f, 0.f, 0.f}, a1 = {0.f, 0.f, 0.f, 0.f};
  a0 = MFMA16(*reinterpret_cast<const bf16x8*>(p0 + off),       af[0], a0);
  a1 = MFMA16(*reinterpret_cast<const bf16x8*>(p1 + off),       af[1], a1);
  a0 = MFMA16(*reinterpret_cast<const bf16x8*>(p0 + off + 64),  af[2], a0);
  a1 = MFMA16(*reinterpret_cast<const bf16x8*>(p1 + off + 64),  af[3], a1);
  a0 = MFMA16(*reinterpret_cast<const bf16x8*>(p0 + off + 128), af[4], a0);
  a1 = MFMA16(*reinterpret_cast<const bf16x8*>(p1 + off + 128), af[5], a1);
  return a0 + a1;
}
__device__ __forceinline__ f32x4 gemm6_af_w(const short* __restrict__ p0,
                                            const short* __restrict__ p1, int off,
                                            const bf16x8* __restrict__ af) {
  f32x4 a0 = {0.f, 0.f, 0.f, 0.f}, a1 = {0.f, 0.f, 0.f, 0.f};
  a0 = MFMA16(af[0], *reinterpret_cast<const bf16x8*>(p0 + off),       a0);
  a1 = MFMA16(af[1], *reinterpret_cast<const bf16x8*>(p1 + off),       a1);
  a0 = MFMA16(af[2], *reinterpret_cast<const bf16x8*>(p0 + off + 64),  a0);
  a1 = MFMA16(af[3], *reinterpret_cast<const bf16x8*>(p1 + off + 64),  a1);
  a0 = MFMA16(af[4], *reinterpret_cast<const bf16x8*>(p0 + off + 128), a0);
  a1 = MFMA16(af[5], *reinterpret_cast<const bf16x8*>(p1 + off + 128), a1);
  return a0 + a1;
}

#define GLOAD16(g, l) __builtin_amdgcn_global_load_lds( \
    (const __attribute__((address_space(1))) void*)(g), \
    (__attribute__((address_space(3))) void*)(l), 16, 0, 0)

// Pre-convert + pre-swizzle weights into 48 chunks of 16x192 bf16 (as r9-r15).
__global__ void wconv_kernel(const float* __restrict__ qkv_w,
                             const float* __restrict__ proj_w,
                             short* __restrict__ ws) {
  const int r = blockIdx.x, c = threadIdx.x;   // 768 x 192
  int chunk, lr;
  float val;
  if (r < 192)      { chunk = r >> 4; lr = r & 15; val = qkv_w[r * CDIM + c]; }
  else if (r < 384) { int q = r - 192; int h = q >> 5; int rr = q & 31;
                      chunk = 12 + 4 * h + (rr >> 4); lr = rr & 15; val = qkv_w[r * CDIM + c]; }
  else if (r < 576) { int q = r - 384; int h = q >> 5; int rr = q & 31;
                      chunk = 14 + 4 * h + (rr >> 4); lr = rr & 15; val = qkv_w[r * CDIM + c]; }
  else              { int q = r - 576; chunk = 36 + (q >> 4); lr = q & 15; val = proj_w[q * CDIM + c]; }
  const int s = c >> 3, lo = c & 7;
  const int sp = (s & 24) | ((s ^ lr) & 7);
  ws[chunk * CHUNK + lr * CDIM + sp * 8 + lo] = f2bf(val);
}

__global__ __launch_bounds__(256, 4)
void winattn_kernel(const float* __restrict__ x, const float* __restrict__ mask,
                    const short* __restrict__ ws,
                    const float* __restrict__ qkv_b, const float* __restrict__ proj_b,
                    float* __restrict__ out) {
  __shared__ __align__(16) short wb[4 * BUF];      // 4-buffer rotation, buf = c&3
  __shared__ __align__(16) short kh[NTOK * KROW];  // current head K [tok][32ch]
  __shared__ __align__(16) short vth[32 * VROW];   // current head V^T [ch][tok]

  const int b    = blockIdx.x;
  const int tid  = threadIdx.x;
  const int lane = tid & 63;
  const int l16  = lane & 15;
  const int g4   = lane >> 4;
  const int m0   = (tid >> 6) * 16;
  const float scale = 0.17677669529663687f;  // 32^-0.5
  const int s0 = (((2 * g4) & 3) << 4) + l16;
  const int hiSel = g4 >> 1;

  // swizzled weight-read base pair (buffer selected by compile-time offset)
  const int t0 = ((g4 ^ l16) & 7) << 3;            // shorts
  const short* rw0 = wb + l16 * CDIM + t0;
  const short* rw1 = wb + l16 * CDIM + (t0 ^ 32);
  // kh / vth access bases
  const short* khr = kh + l16 * KROW + g4 * 8;           // QK reads: +rt*16*KROW
  short*       khw = kh + (m0 + l16) * KROW + 4 * g4;    // K writes: +{0,16}
  const short* vtr = vth + l16 * VROW + g4 * 8;          // PV reads: +ct2*16*VROW+{0,32}
  short*       vtw = vth + l16 * VROW + m0 + 4 * g4;     // V writes: +{0,16*VROW}
  // staging offsets
  const int gofs = (tid >> 6) * 512 + lane * 8;          // global shorts
  short* const lw = wb + (tid >> 6) * 512;               // LDS base (wave-uniform)
  const bool tail = (tid >> 6) < 2;

#define STAGE(cidx) do { \
    const int _lb = ((cidx) & 3) * BUF; \
    GLOAD16(ws + (cidx) * CHUNK + gofs, lw + _lb); \
    if (tail) GLOAD16(ws + (cidx) * CHUNK + gofs + 2048, lw + _lb + 2048); \
  } while (0)

  // ---- prologue: prime all four buffers (chunks 0..3), then x->af ----
  STAGE(0); STAGE(1); STAGE(2); STAGE(3);

  const float* xr = x + (size_t)b * (NTOK * CDIM) + (m0 + l16) * CDIM;
  bf16x8 af[6];
  #pragma unroll
  for (int ks = 0; ks < 6; ++ks) {
    const float4 v0 = *reinterpret_cast<const float4*>(xr + ks * 32 + g4 * 8);
    const float4 v1 = *reinterpret_cast<const float4*>(xr + ks * 32 + g4 * 8 + 4);
    uint32_t t[4];
    t[0] = pack2(v0.x, v0.y); t[1] = pack2(v0.z, v0.w);
    t[2] = pack2(v1.x, v1.y); t[3] = pack2(v1.z, v1.w);
    af[ks] = *reinterpret_cast<bf16x8*>(t);
  }
  const float* mrowl = mask + (size_t)b * (NTOK * NTOK) + (m0 + l16) * NTOK;

  __syncthreads();                             // chunks 0..3 resident

  // ---- Q phases: chunks 0..11; barrier+stage after each ODD phase ----
  bf16x8 aq[6];
  uint32_t ue0 = 0, ue1 = 0;
  #pragma unroll
  for (int c = 0; c < 12; ++c) {
    const int off = (c & 3) * BUF;
    f32x4 acc = gemm6_w_af(rw0, rw1, off, af);
    const float4 bq = *reinterpret_cast<const float4*>(qkv_b + 16 * c + 4 * g4);
    const uint32_t u0 = pack2((acc[0] + bq.x) * scale, (acc[1] + bq.y) * scale);
    const uint32_t u1 = pack2((acc[2] + bq.z) * scale, (acc[3] + bq.w) * scale);
    if (c & 1) {
      aq[c >> 1] = xpose(ue0, ue1, u0, u1, s0, hiSel);
      __syncthreads();                         // phases c-1,c retired; c+1,c+2 resident
      STAGE(c + 3); STAGE(c + 4);              // into the two freed buffers
    } else { ue0 = u0; ue1 = u1; }
  }

  // ---- head loop: A1[K-lo + PV(h-1)] A2[K-hi] | barrier | B1[V-lo + QK+sm]
  //      B2[V-hi] | barrier.  Chunk c0=12+4h -> bufs 0,1,2,3 fixed. ----
  bf16x8 of[6];
  bf16x8 bpa, bpb;
  float rinvP = 1.f;                           // deferred softmax normalizer
  #pragma unroll
  for (int h = 0; h < 6; ++h) {
    const int c0 = 12 + 4 * h;
    // == A1: K cols 0-15 (buf 0) + PV(h-1) ==
    {
      f32x4 acc = gemm6_w_af(rw0, rw1, 0 * BUF, af);
      const float4 bk4 = *reinterpret_cast<const float4*>(qkv_b + 192 + 32 * h + 4 * g4);
      uint2 kw;
      kw.x = pack2(acc[0] + bk4.x, acc[1] + bk4.y);
      kw.y = pack2(acc[2] + bk4.z, acc[3] + bk4.w);
      *reinterpret_cast<uint2*>(khw) = kw;
    }
    if (h > 0) {                               // PV(h-1); apply deferred rinvP
      uint32_t uo[2][2];
      #pragma unroll
      for (int ct2 = 0; ct2 < 2; ++ct2) {
        const short* vb = vtr + ct2 * (16 * VROW);
        f32x4 acc = {0.f, 0.f, 0.f, 0.f};
        acc = MFMA16(*reinterpret_cast<const bf16x8*>(vb),      bpa, acc);
        acc = MFMA16(*reinterpret_cast<const bf16x8*>(vb + 32), bpb, acc);
        uo[ct2][0] = pack2(acc[0] * rinvP, acc[1] * rinvP);
        uo[ct2][1] = pack2(acc[2] * rinvP, acc[3] * rinvP);
      }
      of[h - 1] = xpose(uo[0][0], uo[0][1], uo[1][0], uo[1][1], s0, hiSel);
    }
    // == A2: K cols 16-31 (buf 1) ==
    {
      f32x4 acc = gemm6_w_af(rw0, rw1, 1 * BUF, af);
      const float4 bk4 = *reinterpret_cast<const float4*>(qkv_b + 192 + 32 * h + 16 + 4 * g4);
      uint2 kw;
      kw.x = pack2(acc[0] + bk4.x, acc[1] + bk4.y);
      kw.y = pack2(acc[2] + bk4.z, acc[3] + bk4.w);
      *reinterpret_cast<uint2*>(khw + 16) = kw;
    }
    __syncthreads();                           // kh complete; V-lo/V-hi resident
    STAGE(c0 + 4); STAGE(c0 + 5);              // next A1/A2 (or proj 36,37)

    // == B1: V chs 0-15 (buf 2) + QK + softmax (deferred-rinv) ==
    float4 mreg[4];
    #pragma unroll
    for (int rt = 0; rt < 4; ++rt)
      mreg[rt] = *reinterpret_cast<const float4*>(mrowl + 16 * rt + 4 * g4);
    {
      f32x4 acc = gemm6_af_w(rw0, rw1, 2 * BUF, af);
      const float bv = qkv_b[384 + 32 * h + l16];
      uint2 vw;
      vw.x = pack2(acc[0] + bv, acc[1] + bv);
      vw.y = pack2(acc[2] + bv, acc[3] + bv);
      *reinterpret_cast<uint2*>(vtw) = vw;
    }
    {
      float pr[4][4];
      float rmax = -1e30f;
      #pragma unroll
      for (int rt = 0; rt < 4; ++rt) {
        f32x4 z = {0.f, 0.f, 0.f, 0.f};
        f32x4 s = MFMA16(*reinterpret_cast<const bf16x8*>(khr + rt * (16 * KROW)), aq[h], z);
        pr[rt][0] = s[0] + mreg[rt].x; pr[rt][1] = s[1] + mreg[rt].y;
        pr[rt][2] = s[2] + mreg[rt].z; pr[rt][3] = s[3] + mreg[rt].w;
        #pragma unroll
        for (int i = 0; i < 4; ++i) rmax = fmaxf(rmax, pr[rt][i]);
      }
      rmax = fmaxf(rmax, __shfl_xor(rmax, 16));
      rmax = fmaxf(rmax, __shfl_xor(rmax, 32));
      float rsum = 0.f;
      #pragma unroll
      for (int rt = 0; rt < 4; ++rt)
        #pragma unroll
        for (int i = 0; i < 4; ++i) { pr[rt][i] = __expf(pr[rt][i] - rmax); rsum += pr[rt][i]; }
      uint32_t wpk[4][2];
      #pragma unroll
      for (int rt = 0; rt < 4; ++rt) {
        wpk[rt][0] = pack2(pr[rt][0], pr[rt][1]);
        wpk[rt][1] = pack2(pr[rt][2], pr[rt][3]);
      }
      bpa = xpose(wpk[0][0], wpk[0][1], wpk[1][0], wpk[1][1], s0, hiSel);
      bpb = xpose(wpk[2][0], wpk[2][1], wpk[3][0], wpk[3][1], s0, hiSel);
      rsum += __shfl_xor(rsum, 16);
      rsum += __shfl_xor(rsum, 32);
      rinvP = 1.f / rsum;
    }
    // == B2: V chs 16-31 (buf 3) ==
    {
      f32x4 acc = gemm6_af_w(rw0, rw1, 3 * BUF, af);
      const float bv = qkv_b[384 + 32 * h + 16 + l16];
      uint2 vw;
      vw.x = pack2(acc[0] + bv, acc[1] + bv);
      vw.y = pack2(acc[2] + bv, acc[3] + bv);
      *reinterpret_cast<uint2*>(vtw + 16 * VROW) = vw;
    }
    __syncthreads();                           // vth complete; next A-pair resident
    STAGE(c0 + 6); STAGE(c0 + 7);              // next B1/B2 (or proj 38,39)
  }

  // ---- proj phases: chunks 36..47; PV(5) in first; barrier per pair ----
  // proj operand order: mfma(of, wf) — of as A (r10/r12-validated).
  float* og = out + (size_t)b * (NTOK * CDIM);
  #pragma unroll
  for (int j = 0; j < 12; ++j) {
    const int c = 36 + j;
    const int off = (c & 3) * BUF;
    if (j == 0) {                              // PV(5) -> of[5], apply rinvP
      uint32_t uo[2][2];
      #pragma unroll
      for (int ct2 = 0; ct2 < 2; ++ct2) {
        const short* vb = vtr + ct2 * (16 * VROW);
        f32x4 acc = {0.f, 0.f, 0.f, 0.f};
        acc = MFMA16(*reinterpret_cast<const bf16x8*>(vb),      bpa, acc);
        acc = MFMA16(*reinterpret_cast<const bf16x8*>(vb + 32), bpb, acc);
        uo[ct2][0] = pack2(acc[0] * rinvP, acc[1] * rinvP);
        uo[ct2][1] = pack2(acc[2] * rinvP, acc[3] * rinvP);
      }
      of[5] = xpose(uo[0][0], uo[0][1], uo[1][0], uo[1][1], s0, hiSel);
    }
    f32x4 acc = gemm6_af_w(rw0, rw1, off, of);
    const int cc = 16 * j + l16;
    const float pb = proj_b[cc];
    #pragma unroll
    for (int i = 0; i < 4; ++i)
      og[(m0 + 4 * g4 + i) * CDIM + cc] = acc[i] + pb;
    if ((j & 1) && j < 11) {
      __syncthreads();                         // pair retired; next pair resident
      if (c + 3 < 48) { STAGE(c + 3); STAGE(c + 4); }
    }
  }
#undef STAGE
}

extern "C" void kernel_launch(void* const* d_in, const int* in_sizes, int n_in,
                              void* d_out, int out_size, void* d_ws, size_t ws_size,
                              hipStream_t stream) {
  const float* x      = (const float*)d_in[0];
  const float* mask   = (const float*)d_in[1];
  const float* qkv_w  = (const float*)d_in[2];
  const float* qkv_b  = (const float*)d_in[3];
  const float* proj_w = (const float*)d_in[4];
  const float* proj_b = (const float*)d_in[5];
  float* out = (float*)d_out;

  short* ws = (short*)d_ws;                    // 48 chunks x 3072 shorts = 294912 B

  wconv_kernel<<<768, 192, 0, stream>>>(qkv_w, proj_w, ws);
  winattn_kernel<<<4096, 256, 0, stream>>>(x, mask, ws, qkv_b, proj_b, out);
}

// Round 17
// 207.161 us; speedup vs baseline: 1.0303x; 1.0303x over previous
//
#include <hip/hip_runtime.h>
#include <hip/hip_bf16.h>
#include <stdint.h>

// WindowAttention: B_=4096 windows, N=64 tokens, C=192, H=6 heads, hd=32.
// FINAL (champion = round 12, timed 207.4us, absmax 9.8e-4):
// One block per window, 256 thr / 4 waves. All weights pre-converted to bf16
// and pre-swizzled in workspace; staged via global_load_lds into a ping-pong
// pair of 6KB LDS buffers (one barrier per 16-col chunk, stage issued a full
// phase ahead). q/o live in registers via shfl-transpose (xpose); softmax
// fully in-register via S^T = mfma(K, q). 22KB LDS.
//
// Structural plateau analysis (r12-r16 all 268-281us rocprof):
//  - LDS data-path ~69% busy: 4x weight-read amplification is structural
//    (4 waves split rows; each reads the full staged weight panel).
//  - Occupancy pinned by VGPR=64 allocation tier (launch_bounds(256,4) cap);
//    any tighter cap spills (r6/r9/r13: +0.8-1GB scratch traffic).
//  - Barrier count, stage latency, softmax path, MFMA chain depth: all
//    tested neutral (r8/r14/r15/r16).

#define NTOK 64
#define CDIM 192
#define KROW 40           // kh row stride (shorts): 80 B
#define VROW 72           // vth row stride (shorts): 144 B
#define CHUNK 3072        // shorts per 16x192 chunk

typedef __attribute__((ext_vector_type(4))) float f32x4;
typedef __attribute__((ext_vector_type(8))) short bf16x8;

__device__ __forceinline__ short f2bf(float f) {
  __hip_bfloat16 h = __float2bfloat16(f);
  return *reinterpret_cast<short*>(&h);
}
__device__ __forceinline__ uint32_t pack2(float a, float b) {
  __hip_bfloat162 h2;
  h2.x = __float2bfloat16(a);
  h2.y = __float2bfloat16(b);                      // fuses to v_cvt_pk_bf16_f32
  return *reinterpret_cast<uint32_t*>(&h2);
}

// Cross-lane transpose (validated r2-r16).
__device__ __forceinline__ bf16x8 xpose(uint32_t A0, uint32_t A1,
                                        uint32_t B0, uint32_t B1,
                                        int s0, int hiSel) {
  uint32_t w[4];
  uint32_t a, b;
  a = (uint32_t)__shfl((int)A0, s0);      b = (uint32_t)__shfl((int)B0, s0);      w[0] = hiSel ? b : a;
  a = (uint32_t)__shfl((int)A1, s0);      b = (uint32_t)__shfl((int)B1, s0);      w[1] = hiSel ? b : a;
  a = (uint32_t)__shfl((int)A0, s0 + 16); b = (uint32_t)__shfl((int)B0, s0 + 16); w[2] = hiSel ? b : a;
  a = (uint32_t)__shfl((int)A1, s0 + 16); b = (uint32_t)__shfl((int)B1, s0 + 16); w[3] = hiSel ? b : a;
  return *reinterpret_cast<bf16x8*>(w);
}

#define MFMA16(A, B, C) __builtin_amdgcn_mfma_f32_16x16x32_bf16((A), (B), (C), 0, 0, 0)

// 6-step K=192 GEMM, weight as A-operand (Q/K GEMMs).
__device__ __forceinline__ f32x4 gemm6_w_af(const short* __restrict__ p0,
                                            const short* __restrict__ p1,
                                            const bf16x8* __restrict__ af) {
  f32x4 acc = {0.f, 0.f, 0.f, 0.f};
  acc = MFMA16(*reinterpret_cast<const bf16x8*>(p0),       af[0], acc);
  acc = MFMA16(*reinterpret_cast<const bf16x8*>(p1),       af[1], acc);
  acc = MFMA16(*reinterpret_cast<const bf16x8*>(p0 + 64),  af[2], acc);
  acc = MFMA16(*reinterpret_cast<const bf16x8*>(p1 + 64),  af[3], acc);
  acc = MFMA16(*reinterpret_cast<const bf16x8*>(p0 + 128), af[4], acc);
  acc = MFMA16(*reinterpret_cast<const bf16x8*>(p1 + 128), af[5], acc);
  return acc;
}
// Same, weight as B-operand (V GEMM and PROJ — of/af as A).
__device__ __forceinline__ f32x4 gemm6_af_w(const short* __restrict__ p0,
                                            const short* __restrict__ p1,
                                            const bf16x8* __restrict__ af) {
  f32x4 acc = {0.f, 0.f, 0.f, 0.f};
  acc = MFMA16(af[0], *reinterpret_cast<const bf16x8*>(p0),       acc);
  acc = MFMA16(af[1], *reinterpret_cast<const bf16x8*>(p1),       acc);
  acc = MFMA16(af[2], *reinterpret_cast<const bf16x8*>(p0 + 64),  acc);
  acc = MFMA16(af[3], *reinterpret_cast<const bf16x8*>(p1 + 64),  acc);
  acc = MFMA16(af[4], *reinterpret_cast<const bf16x8*>(p0 + 128), acc);
  acc = MFMA16(af[5], *reinterpret_cast<const bf16x8*>(p1 + 128), acc);
  return acc;
}

#define GLOAD16(g, l) __builtin_amdgcn_global_load_lds( \
    (const __attribute__((address_space(1))) void*)(g), \
    (__attribute__((address_space(3))) void*)(l), 16, 0, 0)

// Pre-convert + pre-swizzle weights into 48 chunks of 16x192 bf16.
// chunks: 0..11 Wq | per head h: 12+4h={Wk lo,hi} 14+4h={Wv lo,hi} | 36..47 Wp
// Slot swizzle within chunk: s' = (s&24) | ((s^row)&7), 16B slots.
__global__ void wconv_kernel(const float* __restrict__ qkv_w,
                             const float* __restrict__ proj_w,
                             short* __restrict__ ws) {
  const int r = blockIdx.x, c = threadIdx.x;   // 768 x 192
  int chunk, lr;
  float val;
  if (r < 192)      { chunk = r >> 4; lr = r & 15; val = qkv_w[r * CDIM + c]; }
  else if (r < 384) { int q = r - 192; int h = q >> 5; int rr = q & 31;
                      chunk = 12 + 4 * h + (rr >> 4); lr = rr & 15; val = qkv_w[r * CDIM + c]; }
  else if (r < 576) { int q = r - 384; int h = q >> 5; int rr = q & 31;
                      chunk = 14 + 4 * h + (rr >> 4); lr = rr & 15; val = qkv_w[r * CDIM + c]; }
  else              { int q = r - 576; chunk = 36 + (q >> 4); lr = q & 15; val = proj_w[q * CDIM + c]; }
  const int s = c >> 3, lo = c & 7;
  const int sp = (s & 24) | ((s ^ lr) & 7);
  ws[chunk * CHUNK + lr * CDIM + sp * 8 + lo] = f2bf(val);
}

__global__ __launch_bounds__(256, 4)
void winattn_kernel(const float* __restrict__ x, const float* __restrict__ mask,
                    const short* __restrict__ ws,
                    const float* __restrict__ qkv_b, const float* __restrict__ proj_b,
                    float* __restrict__ out) {
  __shared__ __align__(16) short wbA[16 * CDIM];   // ping (even chunks)
  __shared__ __align__(16) short wbB[16 * CDIM];   // pong (odd chunks)
  __shared__ __align__(16) short kh[NTOK * KROW];  // current head K [tok][32ch]
  __shared__ __align__(16) short vth[32 * VROW];   // current head V^T [ch][tok]

  const int b    = blockIdx.x;
  const int tid  = threadIdx.x;
  const int lane = tid & 63;
  const int l16  = lane & 15;
  const int g4   = lane >> 4;
  const int m0   = (tid >> 6) * 16;
  const float scale = 0.17677669529663687f;  // 32^-0.5
  const int s0 = (((2 * g4) & 3) << 4) + l16;
  const int hiSel = g4 >> 1;

  // swizzled weight-read bases
  const int t0 = ((g4 ^ l16) & 7) << 3;            // shorts
  const short* rA0 = wbA + l16 * CDIM + t0;
  const short* rA1 = wbA + l16 * CDIM + (t0 ^ 32);
  const short* rB0 = wbB + l16 * CDIM + t0;
  const short* rB1 = wbB + l16 * CDIM + (t0 ^ 32);
  // kh / vth access bases
  const short* khr = kh + l16 * KROW + g4 * 8;           // QK reads: +rt*16*KROW
  short*       khw = kh + (m0 + l16) * KROW + 4 * g4;    // K writes: +{0,16}
  const short* vtr = vth + l16 * VROW + g4 * 8;          // PV reads: +ct2*16*VROW+{0,32}
  short*       vtw = vth + l16 * VROW + m0 + 4 * g4;     // V writes: +{0,16*VROW}
  // staging offsets
  const int gofs = (tid >> 6) * 512 + lane * 8;          // global shorts
  const int lofs = (tid >> 6) * 512;                     // LDS shorts (wave-uniform)
  const bool tail = (tid >> 6) < 2;

  // ---- prologue: prime both buffers, then x->af ----
  {
    GLOAD16(ws + gofs, wbA + lofs);
    if (tail) GLOAD16(ws + gofs + 2048, wbA + lofs + 2048);
    GLOAD16(ws + CHUNK + gofs, wbB + lofs);
    if (tail) GLOAD16(ws + CHUNK + gofs + 2048, wbB + lofs + 2048);
  }
  const float* xr = x + (size_t)b * (NTOK * CDIM) + (m0 + l16) * CDIM;
  bf16x8 af[6];
  #pragma unroll
  for (int ks = 0; ks < 6; ++ks) {
    const float4 v0 = *reinterpret_cast<const float4*>(xr + ks * 32 + g4 * 8);
    const float4 v1 = *reinterpret_cast<const float4*>(xr + ks * 32 + g4 * 8 + 4);
    uint32_t t[4];
    t[0] = pack2(v0.x, v0.y); t[1] = pack2(v0.z, v0.w);
    t[2] = pack2(v1.x, v1.y); t[3] = pack2(v1.z, v1.w);
    af[ks] = *reinterpret_cast<bf16x8*>(t);
  }
  const float* mrowl = mask + (size_t)b * (NTOK * NTOK) + (m0 + l16) * NTOK;

  __syncthreads();                             // chunks 0,1 resident

#define STAGE(dst, cidx) do { \
    GLOAD16(ws + (cidx) * CHUNK + gofs, (dst) + lofs); \
    if (tail) GLOAD16(ws + (cidx) * CHUNK + gofs + 2048, (dst) + lofs + 2048); \
  } while (0)

  // ---- Q phases: chunks 0..11, 16 q-cols each; aq[j] from chunk pair ----
  bf16x8 aq[6];
  uint32_t ue0 = 0, ue1 = 0;
  #pragma unroll
  for (int c = 0; c < 12; ++c) {
    const bool odd = (c & 1);
    f32x4 acc = odd ? gemm6_w_af(rB0, rB1, af) : gemm6_w_af(rA0, rA1, af);
    const float4 bq = *reinterpret_cast<const float4*>(qkv_b + 16 * c + 4 * g4);
    const uint32_t u0 = pack2((acc[0] + bq.x) * scale, (acc[1] + bq.y) * scale);
    const uint32_t u1 = pack2((acc[2] + bq.z) * scale, (acc[3] + bq.w) * scale);
    if (odd) aq[c >> 1] = xpose(ue0, ue1, u0, u1, s0, hiSel);
    else     { ue0 = u0; ue1 = u1; }
    __syncthreads();                           // chunk c readers done; c+1 resident
    STAGE(odd ? wbB : wbA, c + 2);             // chunk c+2 into freed buffer
  }

  // ---- head loop: A1[K-lo + PV(h-1)], A2[K-hi], B1[V-lo + QK+sm], B2[V-hi] ----
  bf16x8 of[6];
  bf16x8 bpa, bpb;
  #pragma unroll
  for (int h = 0; h < 6; ++h) {
    const int base = 12 + 4 * h;
    // == A1: K cols 0-15 (wbA) + PV(h-1) ==
    {
      f32x4 acc = gemm6_w_af(rA0, rA1, af);
      const float4 bk4 = *reinterpret_cast<const float4*>(qkv_b + 192 + 32 * h + 4 * g4);
      uint2 kw;
      kw.x = pack2(acc[0] + bk4.x, acc[1] + bk4.y);
      kw.y = pack2(acc[2] + bk4.z, acc[3] + bk4.w);
      *reinterpret_cast<uint2*>(khw) = kw;
    }
    if (h > 0) {                               // PV(h-1)
      uint32_t uo[2][2];
      #pragma unroll
      for (int ct2 = 0; ct2 < 2; ++ct2) {
        const short* vb = vtr + ct2 * (16 * VROW);
        f32x4 acc = {0.f, 0.f, 0.f, 0.f};
        acc = MFMA16(*reinterpret_cast<const bf16x8*>(vb),      bpa, acc);
        acc = MFMA16(*reinterpret_cast<const bf16x8*>(vb + 32), bpb, acc);
        uo[ct2][0] = pack2(acc[0], acc[1]);
        uo[ct2][1] = pack2(acc[2], acc[3]);
      }
      of[h - 1] = xpose(uo[0][0], uo[0][1], uo[1][0], uo[1][1], s0, hiSel);
    }
    __syncthreads();                           // K-lo readers done; K-hi resident
    STAGE(wbA, base + 2);                      // V-lo

    // == A2: K cols 16-31 (wbB) ==
    {
      f32x4 acc = gemm6_w_af(rB0, rB1, af);
      const float4 bk4 = *reinterpret_cast<const float4*>(qkv_b + 192 + 32 * h + 16 + 4 * g4);
      uint2 kw;
      kw.x = pack2(acc[0] + bk4.x, acc[1] + bk4.y);
      kw.y = pack2(acc[2] + bk4.z, acc[3] + bk4.w);
      *reinterpret_cast<uint2*>(khw + 16) = kw;
    }
    __syncthreads();                           // kh complete; V-lo resident
    STAGE(wbB, base + 3);                      // V-hi

    // == B1: V chs 0-15 (wbA) + QK + softmax ==
    {
      f32x4 acc = gemm6_af_w(rA0, rA1, af);
      const float bv = qkv_b[384 + 32 * h + l16];
      uint2 vw;
      vw.x = pack2(acc[0] + bv, acc[1] + bv);
      vw.y = pack2(acc[2] + bv, acc[3] + bv);
      *reinterpret_cast<uint2*>(vtw) = vw;
    }
    {
      float pr[4][4];
      float rmax = -1e30f;
      #pragma unroll
      for (int rt = 0; rt < 4; ++rt) {
        f32x4 z = {0.f, 0.f, 0.f, 0.f};
        f32x4 s = MFMA16(*reinterpret_cast<const bf16x8*>(khr + rt * (16 * KROW)), aq[h], z);
        const float4 mv = *reinterpret_cast<const float4*>(mrowl + 16 * rt + 4 * g4);
        pr[rt][0] = s[0] + mv.x; pr[rt][1] = s[1] + mv.y;
        pr[rt][2] = s[2] + mv.z; pr[rt][3] = s[3] + mv.w;
        #pragma unroll
        for (int i = 0; i < 4; ++i) rmax = fmaxf(rmax, pr[rt][i]);
      }
      rmax = fmaxf(rmax, __shfl_xor(rmax, 16));
      rmax = fmaxf(rmax, __shfl_xor(rmax, 32));
      float rsum = 0.f;
      #pragma unroll
      for (int rt = 0; rt < 4; ++rt)
        #pragma unroll
        for (int i = 0; i < 4; ++i) { pr[rt][i] = __expf(pr[rt][i] - rmax); rsum += pr[rt][i]; }
      rsum += __shfl_xor(rsum, 16);
      rsum += __shfl_xor(rsum, 32);
      const float rinv = 1.f / rsum;
      uint32_t wpk[4][2];
      #pragma unroll
      for (int rt = 0; rt < 4; ++rt) {
        wpk[rt][0] = pack2(pr[rt][0] * rinv, pr[rt][1] * rinv);
        wpk[rt][1] = pack2(pr[rt][2] * rinv, pr[rt][3] * rinv);
      }
      bpa = xpose(wpk[0][0], wpk[0][1], wpk[1][0], wpk[1][1], s0, hiSel);
      bpb = xpose(wpk[2][0], wpk[2][1], wpk[3][0], wpk[3][1], s0, hiSel);
    }
    __syncthreads();                           // V-lo readers + kh reads done
    STAGE(wbA, h < 5 ? base + 4 : 36);

    // == B2: V chs 16-31 (wbB) ==
    {
      f32x4 acc = gemm6_af_w(rB0, rB1, af);
      const float bv = qkv_b[384 + 32 * h + 16 + l16];
      uint2 vw;
      vw.x = pack2(acc[0] + bv, acc[1] + bv);
      vw.y = pack2(acc[2] + bv, acc[3] + bv);
      *reinterpret_cast<uint2*>(vtw + 16 * VROW) = vw;
    }
    __syncthreads();                           // vth complete
    STAGE(wbB, h < 5 ? base + 5 : 37);
  }

  // ---- proj phases: chunks 36..47 (16 out-cols each); PV(5) in first ----
  // proj operand order: mfma(of, wf) — of as A (r10/r12-validated).
  float* og = out + (size_t)b * (NTOK * CDIM);
  #pragma unroll
  for (int j = 0; j < 12; ++j) {
    const bool odd = (j & 1);
    if (j == 0) {                              // PV(5) -> of[5]
      uint32_t uo[2][2];
      #pragma unroll
      for (int ct2 = 0; ct2 < 2; ++ct2) {
        const short* vb = vtr + ct2 * (16 * VROW);
        f32x4 acc = {0.f, 0.f, 0.f, 0.f};
        acc = MFMA16(*reinterpret_cast<const bf16x8*>(vb),      bpa, acc);
        acc = MFMA16(*reinterpret_cast<const bf16x8*>(vb + 32), bpb, acc);
        uo[ct2][0] = pack2(acc[0], acc[1]);
        uo[ct2][1] = pack2(acc[2], acc[3]);
      }
      of[5] = xpose(uo[0][0], uo[0][1], uo[1][0], uo[1][1], s0, hiSel);
    }
    f32x4 acc = odd ? gemm6_af_w(rB0, rB1, of) : gemm6_af_w(rA0, rA1, of);
    const int cc = 16 * j + l16;
    const float pb = proj_b[cc];
    #pragma unroll
    for (int i = 0; i < 4; ++i)
      og[(m0 + 4 * g4 + i) * CDIM + cc] = acc[i] + pb;
    if (j < 10) {
      __syncthreads();                         // chunk readers done; next resident
      STAGE(odd ? wbB : wbA, 38 + j);
    } else if (j == 10) {
      __syncthreads();                         // drain chunk 47 stage
    }
  }
#undef STAGE
}

extern "C" void kernel_launch(void* const* d_in, const int* in_sizes, int n_in,
                              void* d_out, int out_size, void* d_ws, size_t ws_size,
                              hipStream_t stream) {
  const float* x      = (const float*)d_in[0];
  const float* mask   = (const float*)d_in[1];
  const float* qkv_w  = (const float*)d_in[2];
  const float* qkv_b  = (const float*)d_in[3];
  const float* proj_w = (const float*)d_in[4];
  const float* proj_b = (const float*)d_in[5];
  float* out = (float*)d_out;

  short* ws = (short*)d_ws;                    // 48 chunks x 3072 shorts = 294912 B

  wconv_kernel<<<768, 192, 0, stream>>>(qkv_w, proj_w, ws);
  winattn_kernel<<<4096, 256, 0, stream>>>(x, mask, ws, qkv_b, proj_b, out);
}